// Round 1
// baseline (87.293 us; speedup 1.0000x reference)
//
#include <hip/hip_runtime.h>
#include <math.h>

#define B_ 32
#define C_ 64
#define L_ 16384
#define LT 128

typedef __attribute__((ext_vector_type(8))) short short8;
typedef __attribute__((ext_vector_type(4))) float f32x4;

__device__ __forceinline__ unsigned short f2bf(float x) {
  unsigned int u = __builtin_bit_cast(unsigned int, x);
  u += 0x7fffu + ((u >> 16) & 1u);   // RNE
  return (unsigned short)(u >> 16);
}

__device__ __forceinline__ float lrelu(float x) {
  return x >= 0.f ? x : 0.1f * x;
}

// ---------------------------------------------------------------------------
// Prep: kern[b,c,3] = (lrelu(x1 W1^T)) W2^T ; att[b,c] = sigmoid(lrelu(x1 ca1^T) ca2^T)
// ---------------------------------------------------------------------------
__global__ void da_prep(const float* __restrict__ x1,
                        const float* __restrict__ W1,
                        const float* __restrict__ W2,
                        const float* __restrict__ ca_w1,
                        const float* __restrict__ ca_w2,
                        float* __restrict__ kern,
                        float* __restrict__ att) {
  int b = blockIdx.x;      // 32
  int t = threadIdx.x;     // 64
  __shared__ float x1s[64], h[64], a1[8];
  x1s[t] = x1[b * 64 + t];
  __syncthreads();
  {
    const float* w1r = W1 + t * 64;
    float s = 0.f;
    #pragma unroll
    for (int i = 0; i < 64; ++i) s = fmaf(x1s[i], w1r[i], s);
    h[t] = lrelu(s);
  }
  if (t < 8) {
    const float* cw = ca_w1 + t * 64;
    float a = 0.f;
    #pragma unroll
    for (int i = 0; i < 64; ++i) a = fmaf(x1s[i], cw[i], a);
    a1[t] = lrelu(a);
  }
  __syncthreads();
  #pragma unroll
  for (int kk = 0; kk < 3; ++kk) {
    const float* w2r = W2 + (t * 3 + kk) * 64;
    float s2 = 0.f;
    #pragma unroll
    for (int i = 0; i < 64; ++i) s2 = fmaf(h[i], w2r[i], s2);
    kern[(b * 64 + t) * 3 + kk] = s2;
  }
  {
    float a = 0.f;
    #pragma unroll
    for (int r = 0; r < 8; ++r) a = fmaf(a1[r], ca_w2[t * 8 + r], a);
    att[b * 64 + t] = 1.f / (1.f + expf(-a));
  }
}

// ---------------------------------------------------------------------------
// Main: depthwise(3-tap, per-(b,c) kernel) + lrelu + 1x1 conv (bf16 MFMA)
//       + bias + x0*att residual.  One block = one (b, 128-l tile).
// LDS midT: [l][c] bf16, c-contiguous so B-frags are ds_read_b128;
// swizzle halfword index = l*64 + (c ^ ((l&7)<<3))  -> conflict-free.
// ---------------------------------------------------------------------------
__global__ __launch_bounds__(256) void da_main(
    const float* __restrict__ x0,
    const float* __restrict__ conv_w,
    const float* __restrict__ conv_b,
    const float* __restrict__ kern,
    const float* __restrict__ att,
    float* __restrict__ out) {
  __shared__ unsigned short midT[LT * 64];  // 16 KB

  int blk = blockIdx.x;        // 0..4095
  int b = blk >> 7;
  int l0 = (blk & 127) * LT;
  int tid = threadIdx.x;
  int lane = tid & 63;
  int wave = tid >> 6;

  int m_lane = lane & 15;         // MFMA row/col within 16
  int kbase = (lane >> 4) * 8;    // MFMA k base (8 contiguous k per lane)

  // ---- A-frags: conv_w[o][c] -> bf16 registers (L1-resident across blocks)
  short8 af[2][4];                // [kt][mt]
  #pragma unroll
  for (int kt = 0; kt < 2; ++kt) {
    #pragma unroll
    for (int mt = 0; mt < 4; ++mt) {
      const float* wr = conv_w + (mt * 16 + m_lane) * 64 + kt * 32 + kbase;
      float4 wa = *(const float4*)wr;
      float4 wb = *(const float4*)(wr + 4);
      short8 v;
      v[0] = (short)f2bf(wa.x); v[1] = (short)f2bf(wa.y);
      v[2] = (short)f2bf(wa.z); v[3] = (short)f2bf(wa.w);
      v[4] = (short)f2bf(wb.x); v[5] = (short)f2bf(wb.y);
      v[6] = (short)f2bf(wb.z); v[7] = (short)f2bf(wb.w);
      af[kt][mt] = v;
    }
  }

  // ---- Phase A: depthwise conv + lrelu -> midT (bf16)
  {
    int c = lane;                 // channel owned by this thread
    int lc = wave * 32;           // 32 consecutive l per thread
    int gl = l0 + lc;
    const float* xrow = x0 + ((size_t)(b * 64 + c)) * L_ + gl;
    const float* kr = kern + (b * 64 + c) * 3;
    float k0 = kr[0], k1 = kr[1], k2 = kr[2];

    float4 q[8];
    #pragma unroll
    for (int i = 0; i < 8; ++i) q[i] = ((const float4*)xrow)[i];
    float prev = (gl > 0) ? xrow[-1] : 0.f;
    float nxt7 = (gl + 32 < L_) ? xrow[32] : 0.f;

    #pragma unroll
    for (int i = 0; i < 8; ++i) {
      float xa = q[i].x, xb = q[i].y, xc = q[i].z, xd = q[i].w;
      float xm1 = prev;
      if (i > 0) xm1 = q[i - 1].w;     // i is compile-time (unrolled)
      float xp1 = nxt7;
      if (i < 7) xp1 = q[i + 1].x;
      float m0 = fmaf(k0, xm1, fmaf(k1, xa, k2 * xb));
      float m1 = fmaf(k0, xa,  fmaf(k1, xb, k2 * xc));
      float m2 = fmaf(k0, xb,  fmaf(k1, xc, k2 * xd));
      float m3 = fmaf(k0, xc,  fmaf(k1, xd, k2 * xp1));
      int l = lc + 4 * i;
      midT[(l + 0) * 64 + (c ^ (((l + 0) & 7) << 3))] = f2bf(lrelu(m0));
      midT[(l + 1) * 64 + (c ^ (((l + 1) & 7) << 3))] = f2bf(lrelu(m1));
      midT[(l + 2) * 64 + (c ^ (((l + 2) & 7) << 3))] = f2bf(lrelu(m2));
      midT[(l + 3) * 64 + (c ^ (((l + 3) & 7) << 3))] = f2bf(lrelu(m3));
    }
  }
  __syncthreads();

  // ---- Phase B: out[o][l] = sum_c W[o][c] * mid[c][l]  via 16x16x32 bf16 MFMA
  f32x4 acc[4][2];
  #pragma unroll
  for (int mt = 0; mt < 4; ++mt)
    #pragma unroll
    for (int nt = 0; nt < 2; ++nt)
      acc[mt][nt] = (f32x4){0.f, 0.f, 0.f, 0.f};

  int lw = wave * 32;             // 32 l-columns per wave
  #pragma unroll
  for (int kt = 0; kt < 2; ++kt) {
    #pragma unroll
    for (int nt = 0; nt < 2; ++nt) {
      int l = lw + nt * 16 + m_lane;
      int cb = kt * 32 + kbase;
      const short8 bf = *(const short8*)&midT[l * 64 + (cb ^ ((l & 7) << 3))];
      #pragma unroll
      for (int mt = 0; mt < 4; ++mt)
        acc[mt][nt] = __builtin_amdgcn_mfma_f32_16x16x32_bf16(
            af[kt][mt], bf, acc[mt][nt], 0, 0, 0);
    }
  }

  // ---- Epilogue: + conv_b + x0 * att (all f32), coalesced 64B-per-o stores
  int r0 = (lane >> 4) * 4;
  int ln = lane & 15;
  #pragma unroll
  for (int mt = 0; mt < 4; ++mt) {
    #pragma unroll
    for (int r = 0; r < 4; ++r) {
      int o = mt * 16 + r0 + r;
      float bias = conv_b[o];
      float a = att[b * 64 + o];
      const float* x0r = x0 + ((size_t)(b * 64 + o)) * L_ + l0;
      float* outr = out + ((size_t)(b * 64 + o)) * L_ + l0;
      #pragma unroll
      for (int nt = 0; nt < 2; ++nt) {
        int l = lw + nt * 16 + ln;
        outr[l] = acc[mt][nt][r] + bias + x0r[l] * a;
      }
    }
  }
}

extern "C" void kernel_launch(void* const* d_in, const int* in_sizes, int n_in,
                              void* d_out, int out_size, void* d_ws, size_t ws_size,
                              hipStream_t stream) {
  const float* x0     = (const float*)d_in[0];
  const float* x1     = (const float*)d_in[1];
  const float* W1     = (const float*)d_in[2];
  const float* W2     = (const float*)d_in[3];
  const float* conv_w = (const float*)d_in[4];
  const float* conv_b = (const float*)d_in[5];
  const float* ca_w1  = (const float*)d_in[6];
  const float* ca_w2  = (const float*)d_in[7];
  float* out = (float*)d_out;

  float* kern = (float*)d_ws;                 // B*C*3 = 6144 floats
  float* att  = kern + B_ * C_ * 3;           // B*C   = 2048 floats

  da_prep<<<dim3(B_), dim3(64), 0, stream>>>(x1, W1, W2, ca_w1, ca_w2, kern, att);
  da_main<<<dim3(B_ * (L_ / LT)), dim3(256), 0, stream>>>(x0, conv_w, conv_b,
                                                          kern, att, out);
}

// Round 2
// 76.607 us; speedup vs baseline: 1.1395x; 1.1395x over previous
//
#include <hip/hip_runtime.h>
#include <math.h>

#define B_ 32
#define C_ 64
#define L_ 16384
#define LT 128

typedef __attribute__((ext_vector_type(8))) short short8;
typedef __attribute__((ext_vector_type(4))) float f32x4;

__device__ __forceinline__ unsigned short f2bf(float x) {
  unsigned int u = __builtin_bit_cast(unsigned int, x);
  u += 0x7fffu + ((u >> 16) & 1u);   // RNE
  return (unsigned short)(u >> 16);
}

__device__ __forceinline__ float lrelu(float x) {
  return x >= 0.f ? x : 0.1f * x;
}

__device__ __forceinline__ void load_lds_16(const void* g, void* l) {
  __builtin_amdgcn_global_load_lds(
      (const __attribute__((address_space(1))) void*)g,
      (__attribute__((address_space(3))) void*)l, 16, 0, 0);
}

// ---------------------------------------------------------------------------
// Prep: kern[b,c,3] = (lrelu(x1 W1^T)) W2^T ; att[b,c] = sigmoid(lrelu(x1 ca1^T) ca2^T)
// ---------------------------------------------------------------------------
__global__ void da_prep(const float* __restrict__ x1,
                        const float* __restrict__ W1,
                        const float* __restrict__ W2,
                        const float* __restrict__ ca_w1,
                        const float* __restrict__ ca_w2,
                        float* __restrict__ kern,
                        float* __restrict__ att) {
  int b = blockIdx.x;      // 32
  int t = threadIdx.x;     // 64
  __shared__ float x1s[64], h[64], a1[8];
  x1s[t] = x1[b * 64 + t];
  __syncthreads();
  {
    const float* w1r = W1 + t * 64;
    float s = 0.f;
    #pragma unroll
    for (int i = 0; i < 64; ++i) s = fmaf(x1s[i], w1r[i], s);
    h[t] = lrelu(s);
  }
  if (t < 8) {
    const float* cw = ca_w1 + t * 64;
    float a = 0.f;
    #pragma unroll
    for (int i = 0; i < 64; ++i) a = fmaf(x1s[i], cw[i], a);
    a1[t] = lrelu(a);
  }
  __syncthreads();
  #pragma unroll
  for (int kk = 0; kk < 3; ++kk) {
    const float* w2r = W2 + (t * 3 + kk) * 64;
    float s2 = 0.f;
    #pragma unroll
    for (int i = 0; i < 64; ++i) s2 = fmaf(h[i], w2r[i], s2);
    kern[(b * 64 + t) * 3 + kk] = s2;
  }
  {
    float a = 0.f;
    #pragma unroll
    for (int r = 0; r < 8; ++r) a = fmaf(a1[r], ca_w2[t * 8 + r], a);
    att[b * 64 + t] = 1.f / (1.f + expf(-a));
  }
}

// ---------------------------------------------------------------------------
// Main: global_load_lds-staged x0 tile (f32, source-preswizzled), depthwise
// 3-tap + lrelu -> midT (bf16, swizzled), 1x1 conv via 16x16x32 bf16 MFMA,
// epilogue + conv_b + x0*att from LDS.  One block = one (b, 128-l tile).
//
// x0s layout: row c (128 f32, contiguous); 16B chunk p of row c holds global
// chunk (p ^ (c&7)).  Read of global word w: x0s[c*128 + ((w>>2)^(c&7))*4 + (w&3)].
// -> fixed-w b128 reads across c hit 8 distinct 4-bank groups: conflict-free.
// midT: halfword idx = l*64 + (c ^ ((l&7)<<3)) — same as r1, measured 0 conflicts.
// ---------------------------------------------------------------------------
__global__ __launch_bounds__(256) void da_main(
    const float* __restrict__ x0,
    const float* __restrict__ conv_w,
    const float* __restrict__ conv_b,
    const float* __restrict__ kern,
    const float* __restrict__ att,
    float* __restrict__ out) {
  __shared__ float x0s[64 * LT];            // 32 KB
  __shared__ unsigned short midT[LT * 64];  // 16 KB
  __shared__ float cbs[64], atts[64];

  int blk = blockIdx.x;        // 0..4095
  int b = blk >> 7;
  int l0 = (blk & 127) * LT;
  int tid = threadIdx.x;
  int lane = tid & 63;
  int wave = tid >> 6;

  int m_lane = lane & 15;         // MFMA row/col within 16
  int kbase = (lane >> 4) * 8;    // MFMA k base (8 contiguous k per lane)

  // ---- Stage x0 tile: async global->LDS, 8 instrs/wave, 2 rows (1 KB) each.
  {
    int p = lane & 31;            // 16B chunk position within a row
    int rsel = lane >> 5;         // 0/1: which of the 2 rows this lane feeds
    #pragma unroll
    for (int i = 0; i < 8; ++i) {
      int c = wave * 16 + i * 2 + rsel;
      const float* g = x0 + ((size_t)(b * 64 + c)) * L_ + l0 + ((p ^ (c & 7)) << 2);
      load_lds_16(g, &x0s[(wave * 16 + i * 2) * LT]);
    }
  }

  // ---- Small independent loads issued while staging is in flight
  if (tid < 64) {
    cbs[tid] = conv_b[tid];
    atts[tid] = att[b * 64 + tid];
  }
  float k0, k1, k2;
  {
    const float* kr = kern + (b * 64 + lane) * 3;
    k0 = kr[0]; k1 = kr[1]; k2 = kr[2];
  }
  float prev_g = 0.f, nxt_g = 0.f;
  {
    const float* xrow = x0 + ((size_t)(b * 64 + lane)) * L_;
    if (wave == 0 && l0 > 0) prev_g = xrow[l0 - 1];
    if (wave == 3 && l0 + LT < L_) nxt_g = xrow[l0 + LT];
  }

  // ---- A-frags: conv_w[o][c] -> bf16 registers (L2-resident across blocks)
  short8 af[2][4];                // [kt][mt]
  #pragma unroll
  for (int kt = 0; kt < 2; ++kt) {
    #pragma unroll
    for (int mt = 0; mt < 4; ++mt) {
      const float* wr = conv_w + (mt * 16 + m_lane) * 64 + kt * 32 + kbase;
      float4 wa = *(const float4*)wr;
      float4 wb = *(const float4*)(wr + 4);
      short8 v;
      v[0] = (short)f2bf(wa.x); v[1] = (short)f2bf(wa.y);
      v[2] = (short)f2bf(wa.z); v[3] = (short)f2bf(wa.w);
      v[4] = (short)f2bf(wb.x); v[5] = (short)f2bf(wb.y);
      v[6] = (short)f2bf(wb.z); v[7] = (short)f2bf(wb.w);
      af[kt][mt] = v;
    }
  }

  asm volatile("s_waitcnt vmcnt(0)" ::: "memory");
  __syncthreads();

  // ---- Phase A: depthwise conv + lrelu -> midT (bf16). c=lane, w in [w0,w0+32)
  {
    int c = lane;
    int w0 = wave * 32;
    const int rowb = c * LT;
    const int csw = (c & 7) << 2;

    float4 q[8];
    #pragma unroll
    for (int i = 0; i < 8; ++i) {
      int chunk = (w0 >> 2) + i;
      q[i] = *(const float4*)&x0s[rowb + ((chunk << 2) ^ csw)];
    }
    float prev, nxt;
    if (wave == 0) {
      prev = prev_g;
    } else {
      int w = w0 - 1;
      prev = x0s[rowb + ((w & ~3) ^ csw) + (w & 3)];
    }
    if (wave == 3) {
      nxt = nxt_g;
    } else {
      int w = w0 + 32;
      nxt = x0s[rowb + ((w & ~3) ^ csw) + (w & 3)];
    }

    #pragma unroll
    for (int i = 0; i < 8; ++i) {
      float xa = q[i].x, xb = q[i].y, xc = q[i].z, xd = q[i].w;
      float xm1 = prev;
      if (i > 0) xm1 = q[i - 1].w;
      float xp1 = nxt;
      if (i < 7) xp1 = q[i + 1].x;
      float m0 = fmaf(k0, xm1, fmaf(k1, xa, k2 * xb));
      float m1 = fmaf(k0, xa,  fmaf(k1, xb, k2 * xc));
      float m2 = fmaf(k0, xb,  fmaf(k1, xc, k2 * xd));
      float m3 = fmaf(k0, xc,  fmaf(k1, xd, k2 * xp1));
      int l = w0 + 4 * i;
      midT[(l + 0) * 64 + (c ^ (((l + 0) & 7) << 3))] = f2bf(lrelu(m0));
      midT[(l + 1) * 64 + (c ^ (((l + 1) & 7) << 3))] = f2bf(lrelu(m1));
      midT[(l + 2) * 64 + (c ^ (((l + 2) & 7) << 3))] = f2bf(lrelu(m2));
      midT[(l + 3) * 64 + (c ^ (((l + 3) & 7) << 3))] = f2bf(lrelu(m3));
    }
  }
  __syncthreads();

  // ---- Phase B: out[o][l] = sum_c W[o][c] * mid[c][l]  via 16x16x32 bf16 MFMA
  f32x4 acc[4][2];
  #pragma unroll
  for (int mt = 0; mt < 4; ++mt)
    #pragma unroll
    for (int nt = 0; nt < 2; ++nt)
      acc[mt][nt] = (f32x4){0.f, 0.f, 0.f, 0.f};

  int lw = wave * 32;             // 32 l-columns per wave
  #pragma unroll
  for (int kt = 0; kt < 2; ++kt) {
    #pragma unroll
    for (int nt = 0; nt < 2; ++nt) {
      int l = lw + nt * 16 + m_lane;
      int cb = kt * 32 + kbase;
      const short8 bf = *(const short8*)&midT[l * 64 + (cb ^ ((l & 7) << 3))];
      #pragma unroll
      for (int mt = 0; mt < 4; ++mt)
        acc[mt][nt] = __builtin_amdgcn_mfma_f32_16x16x32_bf16(
            af[kt][mt], bf, acc[mt][nt], 0, 0, 0);
    }
  }

  // ---- Epilogue: + conv_b + x0 * att (x0 from LDS, f32), coalesced stores
  int r0 = (lane >> 4) * 4;
  int ln = lane & 15;
  #pragma unroll
  for (int mt = 0; mt < 4; ++mt) {
    #pragma unroll
    for (int r = 0; r < 4; ++r) {
      int o = mt * 16 + r0 + r;
      float bias = cbs[o];
      float a = atts[o];
      const int orow = o * LT;
      const int osw = (o & 7) << 2;
      float* outr = out + ((size_t)(b * 64 + o)) * L_ + l0;
      #pragma unroll
      for (int nt = 0; nt < 2; ++nt) {
        int l = lw + nt * 16 + ln;
        float xv = x0s[orow + ((l & ~3) ^ osw) + (l & 3)];
        outr[l] = acc[mt][nt][r] + bias + xv * a;
      }
    }
  }
}

extern "C" void kernel_launch(void* const* d_in, const int* in_sizes, int n_in,
                              void* d_out, int out_size, void* d_ws, size_t ws_size,
                              hipStream_t stream) {
  const float* x0     = (const float*)d_in[0];
  const float* x1     = (const float*)d_in[1];
  const float* W1     = (const float*)d_in[2];
  const float* W2     = (const float*)d_in[3];
  const float* conv_w = (const float*)d_in[4];
  const float* conv_b = (const float*)d_in[5];
  const float* ca_w1  = (const float*)d_in[6];
  const float* ca_w2  = (const float*)d_in[7];
  float* out = (float*)d_out;

  float* kern = (float*)d_ws;                 // B*C*3 = 6144 floats
  float* att  = kern + B_ * C_ * 3;           // B*C   = 2048 floats

  da_prep<<<dim3(B_), dim3(64), 0, stream>>>(x1, W1, W2, ca_w1, ca_w2, kern, att);
  da_main<<<dim3(B_ * (L_ / LT)), dim3(256), 0, stream>>>(x0, conv_w, conv_b,
                                                          kern, att, out);
}